// Round 1
// baseline (284.527 us; speedup 1.0000x reference)
//
#include <hip/hip_runtime.h>
#include <math.h>

#define NK 1024          // number of knots
#define NB 4096          // acceleration buckets

// ws float layout:
//   [0 .. 1031]     sorted xp (1024) + 8 +inf sentinels (scan overrun pad)
//   [1032 .. 1037]  meta: lo(=xp0), inv_scale, scale, yp0, ypN, xpN
//   [1040 .. 5135]  quads: 1024 x float4 {x1, y1, slope, 0}   (16B aligned)
//   [5136 .. 7183]  table: 4096 ushort (8 KB)
//   [7184 .. 15375] ftab: 4096 x float2 {a (NaN if dirty), c_b} (32 KB)
#define WS_SXP   0
#define WS_META  1032
#define WS_QUAD  1040
#define WS_TAB   5136
#define WS_FTAB  7184

typedef float f4v __attribute__((ext_vector_type(4)));

// Monotone bucket map — MUST be bit-identical between setup (knots) and main
// (queries): table/ftab validity needs  x >= xp[i]  ==>  bucket(x) >= bucket(xp[i]).
// __fsub_rn/__fmul_rn forbid contraction; trunc-toward-zero and clamp are monotone.
__device__ __forceinline__ int bucket_of(float x, float lo, float scale) {
    float t = __fmul_rn(__fsub_rn(x, lo), scale);
    int b = (int)t;
    b = b < 0 ? 0 : b;
    b = b > (NB - 1) ? (NB - 1) : b;
    return b;
}

__global__ __launch_bounds__(1024) void setup_kernel(
        const float* __restrict__ xp_in, const float* __restrict__ yp_in,
        float* __restrict__ wsf)
{
    __shared__ unsigned long long keys[NK];
    __shared__ float sx[NK + 8];
    __shared__ float sy[NK];
    __shared__ float slp[NK];
    __shared__ unsigned short tabs[NB];

    const int t = threadIdx.x;

    // sortable u64 key: IEEE-monotone transformed x bits, index in low 10 bits
    float xv = xp_in[t];
    unsigned int fb  = __float_as_uint(xv);
    unsigned int k32 = (fb & 0x80000000u) ? ~fb : (fb | 0x80000000u);
    keys[t] = ((unsigned long long)k32 << 10) | (unsigned int)t;
    __syncthreads();

    // bitonic sort, 55 fixed stages (replaces histogram+scan+odd-even loop)
    for (int k = 2; k <= NK; k <<= 1) {
        for (int j = k >> 1; j > 0; j >>= 1) {
            int ixj = t ^ j;
            if (ixj > t) {
                unsigned long long a = keys[t], b = keys[ixj];
                bool up = ((t & k) == 0);
                if ((a > b) == up) { keys[t] = b; keys[ixj] = a; }
            }
            __syncthreads();
        }
    }

    unsigned long long key = keys[t];
    unsigned int s32 = (unsigned int)(key >> 10);
    unsigned int xb  = (s32 & 0x80000000u) ? (s32 ^ 0x80000000u) : ~s32;
    float xs = __uint_as_float(xb);
    sx[t] = xs;
    sy[t] = yp_in[(int)(key & (NK - 1))];
    if (t < 8) sx[NK + t] = INFINITY;
    __syncthreads();

    const float lo  = sx[0];          // == xp0 (sorted)
    const float xpN = sx[NK - 1];
    float range = xpN - lo;
    const float scale     = (range > 0.0f) ? ((float)NB / range) : 0.0f;
    const float inv_scale = range * (1.0f / (float)NB);   // /4096 exact (pow2)

    slp[t] = (t < NK - 1) ? (sy[t + 1] - sy[t]) / (sx[t + 1] - sx[t]) : 0.0f;
    __syncthreads();

    // tabs[b] = first index i with bucket_of(sx[i]) >= b  (== #knots in buckets < b)
    for (int k = 0; k < 4; ++k) {
        int b = 4 * t + k;
        int loi = 0, hii = NK;
        while (loi < hii) {
            int mid = (loi + hii) >> 1;
            if (bucket_of(sx[mid], lo, scale) < b) loi = mid + 1; else hii = mid;
        }
        tabs[b] = (unsigned short)loi;
    }
    __syncthreads();

    // per-bucket line table. Bucket is clean iff no INTERIOR knot (i in [1..NK-2])
    // lands in it; xp[0] always lands in bucket 0 and xp[NK-1] in bucket NB-1,
    // and those are not segment splitters (clamp overrides own those regions).
    float2*         ftabg = (float2*)(wsf + WS_FTAB);
    unsigned short* tabg  = (unsigned short*)(wsf + WS_TAB);
    for (int k = 0; k < 4; ++k) {
        int b   = 4 * t + k;
        int ib  = tabs[b];
        int ib1 = (b == NB - 1) ? NK : tabs[b + 1];
        int interior = ib1 - ib - (b == 0 ? 1 : 0) - (b == NB - 1 ? 1 : 0);
        int hi = ib < 1 ? 1 : (ib > NK - 1 ? NK - 1 : ib);
        float2 e;
        if (interior > 0) {
            e.x = __uint_as_float(0x7fc00000u);   // NaN marker -> fallback
            e.y = 0.0f;
        } else {
            // line anchored at bucket-left edge: res = (x - bl)*a + c_b.
            // |bl - x1|*|a| <= segment dy, so no catastrophic cancellation.
            float a  = slp[hi - 1];
            float bl = __fmaf_rn((float)b, inv_scale, lo);  // same formula as main
            e.x = a;
            e.y = __fmaf_rn(bl - sx[hi - 1], a, sy[hi - 1]);
        }
        ftabg[b] = e;
        tabg[b]  = (unsigned short)ib;
    }

    // fallback-side structures + meta
    wsf[t] = sx[t];
    if (t < 8) wsf[NK + t] = INFINITY;
    float4* qg = (float4*)(wsf + WS_QUAD);
    qg[t] = make_float4(sx[t], sy[t], slp[t], 0.0f);
    if (t == 0) {
        wsf[WS_META + 0] = lo;
        wsf[WS_META + 1] = inv_scale;
        wsf[WS_META + 2] = scale;
        wsf[WS_META + 3] = sy[0];
        wsf[WS_META + 4] = sy[NK - 1];
        wsf[WS_META + 5] = xpN;
    }
}

__device__ __forceinline__ float interp_one(
        float x, const float2* __restrict__ ftab,
        const float* __restrict__ gsxp, const float4* __restrict__ gquads,
        const unsigned short* __restrict__ gtab,
        float lo, float inv_scale, float scale, float xpN, float yp0, float ypN)
{
    int b = bucket_of(x, lo, scale);
    float2 e = ftab[b];                                // ONE ds_read_b64
    float bl  = __fmaf_rn((float)b, inv_scale, lo);
    float res = __fmaf_rn(x - bl, e.x, e.y);
    // dirty bucket + truly interior query (~18% of lanes): exact search via
    // L2-resident global side structures (keeps LDS at 32 KB for occupancy)
    if (__builtin_isnan(e.x) && x > lo && x <= xpN) {
        int j = gtab[b];                               // lower bound, <= idx
        for (;;) {
            float s0 = gsxp[j], s1 = gsxp[j + 1], s2 = gsxp[j + 2], s3 = gsxp[j + 3];
            int c = (s0 < x) + (s1 < x) + (s2 < x) + (s3 < x);
            j += c;
            if (c < 4) break;                          // inf sentinels terminate
        }
        int hi = j < 1 ? 1 : (j > NK - 1 ? NK - 1 : j);
        float4 qd = gquads[hi - 1];                    // {x1, y1, slope, 0}
        res = __fmaf_rn(x - qd.x, qd.z, qd.y);
    }
    res = (x <= lo)  ? yp0 : res;   // searchsorted idx == 0
    res = (x >  xpN) ? ypN : res;   // idx == n
    return res;
}

__global__ __launch_bounds__(512, 8) void interp_kernel(
        const f4v* __restrict__ xq, f4v* __restrict__ out,
        const float* __restrict__ wsf, int n4)
{
    __shared__ __align__(16) float2 ftab[NB];          // 32 KB -> 4 blocks/CU, 32 waves
    const int t = threadIdx.x;
    {
        const f4v* src = (const f4v*)(wsf + WS_FTAB);
        f4v*       dst = (f4v*)ftab;
        #pragma unroll
        for (int i = 0; i < 4; ++i) dst[t + 512 * i] = src[t + 512 * i];
    }
    const float lo        = wsf[WS_META + 0];
    const float inv_scale = wsf[WS_META + 1];
    const float scale     = wsf[WS_META + 2];
    const float yp0       = wsf[WS_META + 3];
    const float ypN       = wsf[WS_META + 4];
    const float xpN       = wsf[WS_META + 5];
    const float*          gsxp   = wsf + WS_SXP;
    const float4*         gquads = (const float4*)(wsf + WS_QUAD);
    const unsigned short* gtab   = (const unsigned short*)(wsf + WS_TAB);
    __syncthreads();

    int q = blockIdx.x * 512 + t;
    const int stride = gridDim.x * 512;
    // 2x unroll: both stream loads issue before dependent work (MLP)
    for (; q + stride < n4; q += 2 * stride) {
        f4v xa = __builtin_nontemporal_load(&xq[q]);
        f4v xb = __builtin_nontemporal_load(&xq[q + stride]);
        f4v ra, rb;
        ra.x = interp_one(xa.x, ftab, gsxp, gquads, gtab, lo, inv_scale, scale, xpN, yp0, ypN);
        ra.y = interp_one(xa.y, ftab, gsxp, gquads, gtab, lo, inv_scale, scale, xpN, yp0, ypN);
        ra.z = interp_one(xa.z, ftab, gsxp, gquads, gtab, lo, inv_scale, scale, xpN, yp0, ypN);
        ra.w = interp_one(xa.w, ftab, gsxp, gquads, gtab, lo, inv_scale, scale, xpN, yp0, ypN);
        __builtin_nontemporal_store(ra, &out[q]);
        rb.x = interp_one(xb.x, ftab, gsxp, gquads, gtab, lo, inv_scale, scale, xpN, yp0, ypN);
        rb.y = interp_one(xb.y, ftab, gsxp, gquads, gtab, lo, inv_scale, scale, xpN, yp0, ypN);
        rb.z = interp_one(xb.z, ftab, gsxp, gquads, gtab, lo, inv_scale, scale, xpN, yp0, ypN);
        rb.w = interp_one(xb.w, ftab, gsxp, gquads, gtab, lo, inv_scale, scale, xpN, yp0, ypN);
        __builtin_nontemporal_store(rb, &out[q + stride]);
    }
    for (; q < n4; q += stride) {
        f4v xa = __builtin_nontemporal_load(&xq[q]);
        f4v ra;
        ra.x = interp_one(xa.x, ftab, gsxp, gquads, gtab, lo, inv_scale, scale, xpN, yp0, ypN);
        ra.y = interp_one(xa.y, ftab, gsxp, gquads, gtab, lo, inv_scale, scale, xpN, yp0, ypN);
        ra.z = interp_one(xa.z, ftab, gsxp, gquads, gtab, lo, inv_scale, scale, xpN, yp0, ypN);
        ra.w = interp_one(xa.w, ftab, gsxp, gquads, gtab, lo, inv_scale, scale, xpN, yp0, ypN);
        __builtin_nontemporal_store(ra, &out[q]);
    }
}

extern "C" void kernel_launch(void* const* d_in, const int* in_sizes, int n_in,
                              void* d_out, int out_size, void* d_ws, size_t ws_size,
                              hipStream_t stream)
{
    const float* x  = (const float*)d_in[0];
    const float* xp = (const float*)d_in[1];
    const float* yp = (const float*)d_in[2];
    float* out = (float*)d_out;
    float* wsf = (float*)d_ws;

    setup_kernel<<<1, 1024, 0, stream>>>(xp, yp, wsf);

    const int n4 = out_size / 4;   // 33,554,432 / 4
    interp_kernel<<<1024, 512, 0, stream>>>((const f4v*)x, (f4v*)out, wsf, n4);
}

// Round 2
// 262.317 us; speedup vs baseline: 1.0847x; 1.0847x over previous
//
#include <hip/hip_runtime.h>
#include <math.h>

#define NK 1024          // number of knots
#define NB 4096          // acceleration buckets

// ws float layout:
//   [0 .. 1031]      sorted xp (1024) + 8 +inf sentinels (scan overrun pad)
//   [1032 .. 1037]   meta: lo(=xp0), inv_scale, scale, yp0, ypN, xpN
//   [1040 .. 5135]   quads: 1024 x float4 {x1, y1, slope, 0}   (16B aligned)
//   [5136 .. 13327]  ftab: 4096 x float2 {a, c_b} clean | {NaN, bitcast(j0)} dirty
#define WS_SXP   0
#define WS_META  1032
#define WS_QUAD  1040
#define WS_FTAB  5136

typedef float f4v __attribute__((ext_vector_type(4)));

// Monotone bucket map — MUST be bit-identical between setup (knots) and main
// (queries): ftab validity needs  x >= xp[i]  ==>  bucket(x) >= bucket(xp[i]).
// __fsub_rn/__fmul_rn forbid contraction; trunc-toward-zero and clamp are monotone.
__device__ __forceinline__ int bucket_of(float x, float lo, float scale) {
    float t = __fmul_rn(__fsub_rn(x, lo), scale);
    int b = (int)t;
    b = b < 0 ? 0 : b;
    b = b > (NB - 1) ? (NB - 1) : b;
    return b;
}

// ---------------------------------------------------------------------------
// setup 1/2: register-resident hybrid bitonic sort of (x_bits, idx) u64 keys.
// LDS exchange only for j>=64 (10 steps, 20 barriers); shfl_xor for j<=32.
// ---------------------------------------------------------------------------
__global__ __launch_bounds__(1024) void setup_sort(
        const float* __restrict__ xp_in, const float* __restrict__ yp_in,
        float* __restrict__ wsf)
{
    __shared__ unsigned long long kl[NK];
    __shared__ float sxs[NK];
    __shared__ float sys[NK];

    const int t = threadIdx.x;

    float xv = xp_in[t];
    unsigned int fb  = __float_as_uint(xv);
    unsigned int k32 = (fb & 0x80000000u) ? ~fb : (fb | 0x80000000u);
    unsigned long long key = ((unsigned long long)k32 << 10) | (unsigned int)t;

    for (int k = 2; k <= NK; k <<= 1) {
        const bool dir = ((t & k) == 0);
        for (int j = k >> 1; j >= 64; j >>= 1) {          // cross-wave: LDS
            kl[t] = key;
            __syncthreads();
            unsigned long long p = kl[t ^ j];
            __syncthreads();
            bool lower = ((t & j) == 0);
            bool wmin  = (dir == lower);
            unsigned long long mn = key < p ? key : p;
            unsigned long long mx = key < p ? p : key;
            key = wmin ? mn : mx;
        }
        for (int j = ((k >> 1) >= 64 ? 32 : (k >> 1)); j >= 1; j >>= 1) {  // in-wave
            unsigned long long p = __shfl_xor(key, j, 64);
            bool lower = ((t & j) == 0);
            bool wmin  = (dir == lower);
            unsigned long long mn = key < p ? key : p;
            unsigned long long mx = key < p ? p : key;
            key = wmin ? mn : mx;
        }
    }

    unsigned int idx0 = (unsigned int)(key & (NK - 1));
    unsigned int s32  = (unsigned int)(key >> 10);
    unsigned int xb   = (s32 & 0x80000000u) ? (s32 ^ 0x80000000u) : ~s32;
    float xs = __uint_as_float(xb);
    float ys = yp_in[idx0];                     // stable sort -> matches argsort perm
    sxs[t] = xs; sys[t] = ys;
    __syncthreads();

    float xn = (t < NK - 1) ? sxs[t + 1] : xs;
    float yn = (t < NK - 1) ? sys[t + 1] : ys;
    float slope = (t < NK - 1) ? (yn - ys) / (xn - xs) : 0.0f;

    wsf[WS_SXP + t] = xs;
    if (t < 8) wsf[WS_SXP + NK + t] = INFINITY;            // scan sentinels
    ((float4*)(wsf + WS_QUAD))[t] = make_float4(xs, ys, slope, 0.0f);
    if (t == 0) {
        float lo  = sxs[0];
        float xpN = sxs[NK - 1];
        float range = xpN - lo;
        wsf[WS_META + 0] = lo;
        wsf[WS_META + 1] = range * (1.0f / (float)NB);     // inv_scale (/4096 exact)
        wsf[WS_META + 2] = (range > 0.0f) ? ((float)NB / range) : 0.0f;
        wsf[WS_META + 3] = sys[0];
        wsf[WS_META + 4] = sys[NK - 1];
        wsf[WS_META + 5] = xpN;
    }
}

// ---------------------------------------------------------------------------
// setup 2/2: per-bucket line table, 16 blocks x 256 (one thread per bucket).
// Bucket clean iff no INTERIOR knot splits it (xp[0]/xp[NK-1] land in buckets
// 0/NB-1 by construction and are not segment splitters there).
// ---------------------------------------------------------------------------
__global__ __launch_bounds__(256) void setup_tables(float* __restrict__ wsf)
{
    __shared__ float sxp_s[NK];
    __shared__ int   lb[257];
    __shared__ float meta[6];

    const int tid = threadIdx.x;
    for (int i = tid; i < NK; i += 256) sxp_s[i] = wsf[WS_SXP + i];
    if (tid < 6) meta[tid] = wsf[WS_META + tid];
    __syncthreads();

    const float lo = meta[0], inv_scale = meta[1], scale = meta[2];
    const int base = blockIdx.x * 256;

    auto lbf = [&](int b) -> int {   // first i with bucket_of(sxp[i]) >= b
        int loi = 0, hii = NK;
        while (loi < hii) {
            int mid = (loi + hii) >> 1;
            if (bucket_of(sxp_s[mid], lo, scale) < b) loi = mid + 1; else hii = mid;
        }
        return loi;
    };
    lb[tid] = lbf(base + tid);
    if (tid == 0) lb[256] = (base + 256 >= NB) ? NK : lbf(base + 256);
    __syncthreads();

    const int b   = base + tid;
    const int ib  = lb[tid];
    const int ib1 = lb[tid + 1];
    const int interior = ib1 - ib - (b == 0 ? 1 : 0) - (b == NB - 1 ? 1 : 0);

    float2 e;
    if (interior > 0) {
        e.x = __uint_as_float(0x7fc00000u);                // NaN marker
        e.y = __uint_as_float((unsigned int)ib);           // packed lower bound
    } else {
        int hi = ib < 1 ? 1 : (ib > NK - 1 ? NK - 1 : ib);
        float4 qd = ((const float4*)(wsf + WS_QUAD))[hi - 1];
        // line anchored at bucket-left edge: res = (x - bl)*a + c_b; |bl-x1|*|a|
        // <= segment dy so no catastrophic cancellation.
        float bl = __fmaf_rn((float)b, inv_scale, lo);     // same formula as main
        e.x = qd.z;
        e.y = __fmaf_rn(bl - qd.x, qd.z, qd.y);
    }
    ((float2*)(wsf + WS_FTAB))[b] = e;
}

// ---------------------------------------------------------------------------
// main kernel
// ---------------------------------------------------------------------------
__device__ __forceinline__ float interp_one(
        float x, const float2* __restrict__ ftab, const float* __restrict__ sxp,
        const float4* __restrict__ gquads,
        float lo, float inv_scale, float scale, float xpN, float yp0, float ypN)
{
    int b = bucket_of(x, lo, scale);
    float2 e = ftab[b];                                    // ONE ds_read_b64
    float bl  = __fmaf_rn((float)b, inv_scale, lo);
    float res = __fmaf_rn(x - bl, e.x, e.y);
    // dirty bucket + interior query: LDS scan (j0 packed in e.y) + one L2 quad read
    if (__builtin_isnan(e.x) && x > lo && x <= xpN) {
        int j = (int)__float_as_uint(e.y);
        while (sxp[j] < x) ++j;                            // typ. 1-2 LDS b32 probes
        int hi = j < 1 ? 1 : j;                            // j <= NK-1 here (x<=xpN)
        float4 qd = gquads[hi - 1];                        // 16 KB, L2-hot per XCD
        res = __fmaf_rn(x - qd.x, qd.z, qd.y);
    }
    res = (x <= lo)  ? yp0 : res;   // searchsorted idx == 0
    res = (x >  xpN) ? ypN : res;   // idx == n
    return res;
}

__global__ __launch_bounds__(512, 8) void interp_kernel(
        const f4v* __restrict__ xq, f4v* __restrict__ out,
        const float* __restrict__ wsf, int n4)
{
    __shared__ __align__(16) float2 ftab[NB];              // 32 KB
    __shared__ float sxp_s[NK + 8];                        // 4.1 KB -> 36.9 KB total
    const int t = threadIdx.x;                             // => 4 blocks/CU, 32 waves
    {
        const f4v* src = (const f4v*)(wsf + WS_FTAB);
        f4v*       dst = (f4v*)ftab;
        #pragma unroll
        for (int i = 0; i < 4; ++i) dst[t + 512 * i] = src[t + 512 * i];
        for (int i = t; i < NK + 8; i += 512) sxp_s[i] = wsf[WS_SXP + i];
    }
    const float lo        = wsf[WS_META + 0];
    const float inv_scale = wsf[WS_META + 1];
    const float scale     = wsf[WS_META + 2];
    const float yp0       = wsf[WS_META + 3];
    const float ypN       = wsf[WS_META + 4];
    const float xpN       = wsf[WS_META + 5];
    const float4* gquads  = (const float4*)(wsf + WS_QUAD);
    __syncthreads();

    int q = blockIdx.x * 512 + t;
    const int stride = gridDim.x * 512;
    // 2x unroll: both stream loads issue before dependent work (MLP)
    for (; q + stride < n4; q += 2 * stride) {
        f4v xa = xq[q];
        f4v xb = xq[q + stride];
        f4v ra, rb;
        ra.x = interp_one(xa.x, ftab, sxp_s, gquads, lo, inv_scale, scale, xpN, yp0, ypN);
        ra.y = interp_one(xa.y, ftab, sxp_s, gquads, lo, inv_scale, scale, xpN, yp0, ypN);
        ra.z = interp_one(xa.z, ftab, sxp_s, gquads, lo, inv_scale, scale, xpN, yp0, ypN);
        ra.w = interp_one(xa.w, ftab, sxp_s, gquads, lo, inv_scale, scale, xpN, yp0, ypN);
        rb.x = interp_one(xb.x, ftab, sxp_s, gquads, lo, inv_scale, scale, xpN, yp0, ypN);
        rb.y = interp_one(xb.y, ftab, sxp_s, gquads, lo, inv_scale, scale, xpN, yp0, ypN);
        rb.z = interp_one(xb.z, ftab, sxp_s, gquads, lo, inv_scale, scale, xpN, yp0, ypN);
        rb.w = interp_one(xb.w, ftab, sxp_s, gquads, lo, inv_scale, scale, xpN, yp0, ypN);
        __builtin_nontemporal_store(ra, &out[q]);
        __builtin_nontemporal_store(rb, &out[q + stride]);
    }
    for (; q < n4; q += stride) {
        f4v xa = xq[q];
        f4v ra;
        ra.x = interp_one(xa.x, ftab, sxp_s, gquads, lo, inv_scale, scale, xpN, yp0, ypN);
        ra.y = interp_one(xa.y, ftab, sxp_s, gquads, lo, inv_scale, scale, xpN, yp0, ypN);
        ra.z = interp_one(xa.z, ftab, sxp_s, gquads, lo, inv_scale, scale, xpN, yp0, ypN);
        ra.w = interp_one(xa.w, ftab, sxp_s, gquads, lo, inv_scale, scale, xpN, yp0, ypN);
        __builtin_nontemporal_store(ra, &out[q]);
    }
}

extern "C" void kernel_launch(void* const* d_in, const int* in_sizes, int n_in,
                              void* d_out, int out_size, void* d_ws, size_t ws_size,
                              hipStream_t stream)
{
    const float* x  = (const float*)d_in[0];
    const float* xp = (const float*)d_in[1];
    const float* yp = (const float*)d_in[2];
    float* out = (float*)d_out;
    float* wsf = (float*)d_ws;

    setup_sort<<<1, 1024, 0, stream>>>(xp, yp, wsf);
    setup_tables<<<NB / 256, 256, 0, stream>>>(wsf);

    const int n4 = out_size / 4;   // 33,554,432 / 4 = 8,388,608
    // 1024 blocks x 512 = 524,288 threads -> exactly 16 f4v/thread, no tail
    interp_kernel<<<1024, 512, 0, stream>>>((const f4v*)x, (f4v*)out, wsf, n4);
}

// Round 3
// 259.509 us; speedup vs baseline: 1.0964x; 1.0108x over previous
//
#include <hip/hip_runtime.h>
#include <math.h>

#define NK 1024          // number of knots
#define NB 4096          // acceleration buckets

// ws float layout:
//   [0 .. 1031]      sorted xp (1024) + 8 +inf sentinels
//   [1032 .. 1037]   meta: lo(=xp0), inv_scale, scale, yp0, ypN, xpN
//   [1040 .. 5135]   quads: 1024 x float4 {x1, y1, slope, 0}   (16B aligned)
//   [5136 .. 13327]  ftab: 4096 x float2 {a, c_b} clean | {NaN, bitcast(j0)} dirty
#define WS_SXP   0
#define WS_META  1032
#define WS_QUAD  1040
#define WS_FTAB  5136

typedef float f4v __attribute__((ext_vector_type(4)));

// Monotone bucket map — MUST be bit-identical between setup (knots) and main
// (queries): ftab validity needs  x >= xp[i]  ==>  bucket(x) >= bucket(xp[i]).
// __fsub_rn/__fmul_rn forbid contraction; trunc-toward-zero and clamp are monotone.
__device__ __forceinline__ int bucket_of(float x, float lo, float scale) {
    float t = __fmul_rn(__fsub_rn(x, lo), scale);
    int b = (int)t;
    b = b < 0 ? 0 : b;
    b = b > (NB - 1) ? (NB - 1) : b;
    return b;
}

// ---------------------------------------------------------------------------
// setup 1/2: register-resident hybrid bitonic sort of (x_bits, idx) u64 keys.
// ---------------------------------------------------------------------------
__global__ __launch_bounds__(1024) void setup_sort(
        const float* __restrict__ xp_in, const float* __restrict__ yp_in,
        float* __restrict__ wsf)
{
    __shared__ unsigned long long kl[NK];
    __shared__ float sxs[NK];
    __shared__ float sys[NK];

    const int t = threadIdx.x;

    float xv = xp_in[t];
    unsigned int fb  = __float_as_uint(xv);
    unsigned int k32 = (fb & 0x80000000u) ? ~fb : (fb | 0x80000000u);
    unsigned long long key = ((unsigned long long)k32 << 10) | (unsigned int)t;

    for (int k = 2; k <= NK; k <<= 1) {
        const bool dir = ((t & k) == 0);
        for (int j = k >> 1; j >= 64; j >>= 1) {          // cross-wave: LDS
            kl[t] = key;
            __syncthreads();
            unsigned long long p = kl[t ^ j];
            __syncthreads();
            bool lower = ((t & j) == 0);
            bool wmin  = (dir == lower);
            unsigned long long mn = key < p ? key : p;
            unsigned long long mx = key < p ? p : key;
            key = wmin ? mn : mx;
        }
        for (int j = ((k >> 1) >= 64 ? 32 : (k >> 1)); j >= 1; j >>= 1) {  // in-wave
            unsigned long long p = __shfl_xor(key, j, 64);
            bool lower = ((t & j) == 0);
            bool wmin  = (dir == lower);
            unsigned long long mn = key < p ? key : p;
            unsigned long long mx = key < p ? p : key;
            key = wmin ? mn : mx;
        }
    }

    unsigned int idx0 = (unsigned int)(key & (NK - 1));
    unsigned int s32  = (unsigned int)(key >> 10);
    unsigned int xb   = (s32 & 0x80000000u) ? (s32 ^ 0x80000000u) : ~s32;
    float xs = __uint_as_float(xb);
    float ys = yp_in[idx0];                     // stable sort -> matches argsort perm
    sxs[t] = xs; sys[t] = ys;
    __syncthreads();

    float xn = (t < NK - 1) ? sxs[t + 1] : xs;
    float yn = (t < NK - 1) ? sys[t + 1] : ys;
    float slope = (t < NK - 1) ? (yn - ys) / (xn - xs) : 0.0f;

    wsf[WS_SXP + t] = xs;
    if (t < 8) wsf[WS_SXP + NK + t] = INFINITY;
    ((float4*)(wsf + WS_QUAD))[t] = make_float4(xs, ys, slope, 0.0f);
    if (t == 0) {
        float lo  = sxs[0];
        float xpN = sxs[NK - 1];
        float range = xpN - lo;
        wsf[WS_META + 0] = lo;
        wsf[WS_META + 1] = range * (1.0f / (float)NB);     // inv_scale (/4096 exact)
        wsf[WS_META + 2] = (range > 0.0f) ? ((float)NB / range) : 0.0f;
        wsf[WS_META + 3] = sys[0];
        wsf[WS_META + 4] = sys[NK - 1];
        wsf[WS_META + 5] = xpN;
    }
}

// ---------------------------------------------------------------------------
// setup 2/2: per-bucket line table, 16 blocks x 256 (one thread per bucket).
// ---------------------------------------------------------------------------
__global__ __launch_bounds__(256) void setup_tables(float* __restrict__ wsf)
{
    __shared__ float sxp_s[NK];
    __shared__ int   lb[257];
    __shared__ float meta[6];

    const int tid = threadIdx.x;
    for (int i = tid; i < NK; i += 256) sxp_s[i] = wsf[WS_SXP + i];
    if (tid < 6) meta[tid] = wsf[WS_META + tid];
    __syncthreads();

    const float lo = meta[0], inv_scale = meta[1], scale = meta[2];
    const int base = blockIdx.x * 256;

    auto lbf = [&](int b) -> int {   // first i with bucket_of(sxp[i]) >= b
        int loi = 0, hii = NK;
        while (loi < hii) {
            int mid = (loi + hii) >> 1;
            if (bucket_of(sxp_s[mid], lo, scale) < b) loi = mid + 1; else hii = mid;
        }
        return loi;
    };
    lb[tid] = lbf(base + tid);
    if (tid == 0) lb[256] = (base + 256 >= NB) ? NK : lbf(base + 256);
    __syncthreads();

    const int b   = base + tid;
    const int ib  = lb[tid];
    const int ib1 = lb[tid + 1];
    const int interior = ib1 - ib - (b == 0 ? 1 : 0) - (b == NB - 1 ? 1 : 0);

    float2 e;
    if (interior > 0) {
        e.x = __uint_as_float(0x7fc00000u);                // NaN marker
        e.y = __uint_as_float((unsigned int)ib);           // packed lower bound j0
    } else {
        int hi = ib < 1 ? 1 : (ib > NK - 1 ? NK - 1 : ib);
        float4 qd = ((const float4*)(wsf + WS_QUAD))[hi - 1];
        float bl = __fmaf_rn((float)b, inv_scale, lo);     // same formula as main
        e.x = qd.z;
        e.y = __fmaf_rn(bl - qd.x, qd.z, qd.y);
    }
    ((float2*)(wsf + WS_FTAB))[b] = e;
}

// ---------------------------------------------------------------------------
// main kernel: U queries processed in interleaved phases so the U dependent
// LDS chains pipeline instead of serializing.
// ---------------------------------------------------------------------------
template<int U>
__device__ __forceinline__ void interp_batch(
        const float* xin, float* rout,
        const float2* __restrict__ ftab, const float* __restrict__ sxp,
        const float4* __restrict__ squad,
        float lo, float inv_scale, float scale, float xpN, float yp0, float ypN)
{
    float2 e[U];
    float  res[U];
    int    j[U];
    bool   fb[U];

    // phase A: all buckets + all ftab gathers issued back-to-back
    #pragma unroll
    for (int u = 0; u < U; ++u) {
        int b = bucket_of(xin[u], lo, scale);
        e[u] = ftab[b];
        float bl = __fmaf_rn((float)b, inv_scale, lo);
        res[u] = bl;                       // stash bl; finished in phase B
    }
    // phase B: clean-path fma + fallback mask
    #pragma unroll
    for (int u = 0; u < U; ++u) {
        float bl = res[u];
        res[u] = __fmaf_rn(xin[u] - bl, e[u].x, e[u].y);
        fb[u]  = __builtin_isnan(e[u].x) && (xin[u] > lo) && (xin[u] <= xpN);
        j[u]   = fb[u] ? (int)__float_as_uint(e[u].y) : 0;
    }
    // phase C: 3 fixed interleaved scan rounds (advance iff sxp[j] < x).
    // Unconditional: non-fb lanes walk at most 3 slots from 0 — harmless.
    #pragma unroll
    for (int r = 0; r < 3; ++r) {
        #pragma unroll
        for (int u = 0; u < U; ++u) j[u] += (sxp[j[u]] < xin[u]) ? 1 : 0;
    }
    // rare cleanup (buckets with >3 interior knots); exec-mask mostly empty
    #pragma unroll
    for (int u = 0; u < U; ++u)
        while (fb[u] && sxp[j[u]] < xin[u]) ++j[u];
    // phase D: all quad gathers issued together, branch-free selects
    #pragma unroll
    for (int u = 0; u < U; ++u) {
        int hi = j[u] < 1 ? 1 : j[u];
        float4 qd = squad[hi - 1];
        float rf  = __fmaf_rn(xin[u] - qd.x, qd.z, qd.y);
        res[u] = fb[u] ? rf : res[u];
        res[u] = (xin[u] <= lo)  ? yp0 : res[u];
        res[u] = (xin[u] >  xpN) ? ypN : res[u];
        rout[u] = res[u];
    }
}

__global__ __launch_bounds__(512, 6) void interp_kernel(
        const f4v* __restrict__ xq, f4v* __restrict__ out,
        const float* __restrict__ wsf, int n4)
{
    __shared__ __align__(16) float2 ftab[NB];      // 32 KB
    __shared__ __align__(16) float4 squad[NK];     // 16 KB
    __shared__ float sxp_s[NK];                    // 4 KB  -> 52 KB, 3 blocks/CU
    const int t = threadIdx.x;
    {
        const f4v* fsrc = (const f4v*)(wsf + WS_FTAB);
        f4v*       fdst = (f4v*)ftab;
        #pragma unroll
        for (int i = 0; i < 4; ++i) fdst[t + 512 * i] = fsrc[t + 512 * i];
        const f4v* qsrc = (const f4v*)(wsf + WS_QUAD);
        f4v*       qdst = (f4v*)squad;
        #pragma unroll
        for (int i = 0; i < 2; ++i) qdst[t + 512 * i] = qsrc[t + 512 * i];
        #pragma unroll
        for (int i = 0; i < 2; ++i) sxp_s[t + 512 * i] = wsf[WS_SXP + t + 512 * i];
    }
    const float lo        = wsf[WS_META + 0];
    const float inv_scale = wsf[WS_META + 1];
    const float scale     = wsf[WS_META + 2];
    const float yp0       = wsf[WS_META + 3];
    const float ypN       = wsf[WS_META + 4];
    const float xpN       = wsf[WS_META + 5];
    __syncthreads();

    int q = blockIdx.x * 512 + t;
    const int stride = gridDim.x * 512;
    for (; q + stride < n4; q += 2 * stride) {
        f4v xa = xq[q];
        f4v xb = xq[q + stride];
        float xin[8] = {xa.x, xa.y, xa.z, xa.w, xb.x, xb.y, xb.z, xb.w};
        float r8[8];
        interp_batch<8>(xin, r8, ftab, sxp_s, squad,
                        lo, inv_scale, scale, xpN, yp0, ypN);
        f4v ra = {r8[0], r8[1], r8[2], r8[3]};
        f4v rb = {r8[4], r8[5], r8[6], r8[7]};
        __builtin_nontemporal_store(ra, &out[q]);
        __builtin_nontemporal_store(rb, &out[q + stride]);
    }
    for (; q < n4; q += stride) {
        f4v xa = xq[q];
        float xin[4] = {xa.x, xa.y, xa.z, xa.w};
        float r4[4];
        interp_batch<4>(xin, r4, ftab, sxp_s, squad,
                        lo, inv_scale, scale, xpN, yp0, ypN);
        f4v ra = {r4[0], r4[1], r4[2], r4[3]};
        __builtin_nontemporal_store(ra, &out[q]);
    }
}

extern "C" void kernel_launch(void* const* d_in, const int* in_sizes, int n_in,
                              void* d_out, int out_size, void* d_ws, size_t ws_size,
                              hipStream_t stream)
{
    const float* x  = (const float*)d_in[0];
    const float* xp = (const float*)d_in[1];
    const float* yp = (const float*)d_in[2];
    float* out = (float*)d_out;
    float* wsf = (float*)d_ws;

    setup_sort<<<1, 1024, 0, stream>>>(xp, yp, wsf);
    setup_tables<<<NB / 256, 256, 0, stream>>>(wsf);

    const int n4 = out_size / 4;   // 33,554,432 / 4 = 8,388,608
    // 768 blocks x 512 = 3 blocks/CU exact residency (LDS-limited)
    interp_kernel<<<768, 512, 0, stream>>>((const f4v*)x, (f4v*)out, wsf, n4);
}

// Round 4
// 254.589 us; speedup vs baseline: 1.1176x; 1.0193x over previous
//
#include <hip/hip_runtime.h>
#include <math.h>

#define NK 1024          // number of knots
#define NB 4096          // acceleration buckets

// ws float layout:
//   [0 .. 1031]      sorted xp (1024) + 8 +inf sentinels
//   [1032 .. 1036]   meta: lo(=xp0), scale, yp0, ypN, xpN
//   [1040 .. 5135]   quads: 1024 x float4 {x1, y1, slope, 0}   (16B aligned)
//   [5136 .. 21519]  ftab4: 4096 x float4
//                      cnt<=1 knots: {x_s, y_s, slopeL, slopeR}  (exact answer)
//                      cnt>=2:       {0, 0, NaN, bitcast(j0)}   (fallback)
#define WS_SXP   0
#define WS_META  1032
#define WS_QUAD  1040
#define WS_FTAB  5136

typedef float f4v __attribute__((ext_vector_type(4)));

// Monotone bucket map — MUST be bit-identical between setup (knots) and main
// (queries): ftab validity needs  x >= xp[i]  ==>  bucket(x) >= bucket(xp[i]).
// __fsub_rn/__fmul_rn forbid contraction; trunc-toward-zero and clamp are monotone.
__device__ __forceinline__ int bucket_of(float x, float lo, float scale) {
    float t = __fmul_rn(__fsub_rn(x, lo), scale);
    int b = (int)t;
    b = b < 0 ? 0 : b;
    b = b > (NB - 1) ? (NB - 1) : b;
    return b;
}

// ---------------------------------------------------------------------------
// setup 1/2: register-resident hybrid bitonic sort of (x_bits, idx) u64 keys.
// ---------------------------------------------------------------------------
__global__ __launch_bounds__(1024) void setup_sort(
        const float* __restrict__ xp_in, const float* __restrict__ yp_in,
        float* __restrict__ wsf)
{
    __shared__ unsigned long long kl[NK];
    __shared__ float sxs[NK];
    __shared__ float sys[NK];

    const int t = threadIdx.x;

    float xv = xp_in[t];
    unsigned int fb  = __float_as_uint(xv);
    unsigned int k32 = (fb & 0x80000000u) ? ~fb : (fb | 0x80000000u);
    unsigned long long key = ((unsigned long long)k32 << 10) | (unsigned int)t;

    for (int k = 2; k <= NK; k <<= 1) {
        const bool dir = ((t & k) == 0);
        for (int j = k >> 1; j >= 64; j >>= 1) {          // cross-wave: LDS
            kl[t] = key;
            __syncthreads();
            unsigned long long p = kl[t ^ j];
            __syncthreads();
            bool lower = ((t & j) == 0);
            bool wmin  = (dir == lower);
            unsigned long long mn = key < p ? key : p;
            unsigned long long mx = key < p ? p : key;
            key = wmin ? mn : mx;
        }
        for (int j = ((k >> 1) >= 64 ? 32 : (k >> 1)); j >= 1; j >>= 1) {  // in-wave
            unsigned long long p = __shfl_xor(key, j, 64);
            bool lower = ((t & j) == 0);
            bool wmin  = (dir == lower);
            unsigned long long mn = key < p ? key : p;
            unsigned long long mx = key < p ? p : key;
            key = wmin ? mn : mx;
        }
    }

    unsigned int idx0 = (unsigned int)(key & (NK - 1));
    unsigned int s32  = (unsigned int)(key >> 10);
    unsigned int xb   = (s32 & 0x80000000u) ? (s32 ^ 0x80000000u) : ~s32;
    float xs = __uint_as_float(xb);
    float ys = yp_in[idx0];                     // stable sort -> matches argsort perm
    sxs[t] = xs; sys[t] = ys;
    __syncthreads();

    float xn = (t < NK - 1) ? sxs[t + 1] : xs;
    float yn = (t < NK - 1) ? sys[t + 1] : ys;
    float slope = (t < NK - 1) ? (yn - ys) / (xn - xs) : 0.0f;

    wsf[WS_SXP + t] = xs;
    if (t < 8) wsf[WS_SXP + NK + t] = INFINITY;
    ((float4*)(wsf + WS_QUAD))[t] = make_float4(xs, ys, slope, 0.0f);
    if (t == 0) {
        float lo  = sxs[0];
        float xpN = sxs[NK - 1];
        float range = xpN - lo;
        wsf[WS_META + 0] = lo;
        wsf[WS_META + 1] = (range > 0.0f) ? ((float)NB / range) : 0.0f;  // scale
        wsf[WS_META + 2] = sys[0];
        wsf[WS_META + 3] = sys[NK - 1];
        wsf[WS_META + 4] = xpN;
    }
}

// ---------------------------------------------------------------------------
// setup 2/2: per-bucket float4 entries, 16 blocks x 256 (one thread/bucket).
// cnt = interior knots in bucket (knot 0 always lands in bucket 0, knot NK-1
// in bucket NB-1; neither splits the in-range region there — excluded).
//   cnt==0: single segment (ib-1, ib) covers the bucket -> {x1,y1,a,a}
//   cnt==1: unique interior knot s; both adjacent segments pass through
//           (x_s, y_s) -> {x_s, y_s, slp[s-1], slp[s]}  (exact, no fallback)
//   cnt>=2: NaN marker + packed lower-bound index ib
// ---------------------------------------------------------------------------
__global__ __launch_bounds__(256) void setup_tables(float* __restrict__ wsf)
{
    __shared__ float sxp_s[NK];
    __shared__ int   lb[257];
    __shared__ float meta[5];

    const int tid = threadIdx.x;
    for (int i = tid; i < NK; i += 256) sxp_s[i] = wsf[WS_SXP + i];
    if (tid < 5) meta[tid] = wsf[WS_META + tid];
    __syncthreads();

    const float lo = meta[0], scale = meta[1];
    const int base = blockIdx.x * 256;

    auto lbf = [&](int b) -> int {   // first i with bucket_of(sxp[i]) >= b
        int loi = 0, hii = NK;
        while (loi < hii) {
            int mid = (loi + hii) >> 1;
            if (bucket_of(sxp_s[mid], lo, scale) < b) loi = mid + 1; else hii = mid;
        }
        return loi;
    };
    lb[tid] = lbf(base + tid);
    if (tid == 0) lb[256] = (base + 256 >= NB) ? NK : lbf(base + 256);
    __syncthreads();

    const int b   = base + tid;
    const int ib  = lb[tid];
    const int ib1 = lb[tid + 1];
    const int cnt = ib1 - ib - (b == 0 ? 1 : 0) - (b == NB - 1 ? 1 : 0);

    const float4* gq = (const float4*)(wsf + WS_QUAD);
    float4 e;
    if (cnt <= 0) {
        int hi = ib < 1 ? 1 : (ib > NK - 1 ? NK - 1 : ib);
        float4 qd = gq[hi - 1];                 // {x1, y1, slope}
        e = make_float4(qd.x, qd.y, qd.z, qd.z);
    } else if (cnt == 1) {
        int s = ib + (b == 0 ? 1 : 0);          // s in [1, NK-2] guaranteed
        float4 qs = gq[s];                      // {x_s, y_s, slp[s]}
        float4 qm = gq[s - 1];                  // slp[s-1]
        e = make_float4(qs.x, qs.y, qm.z, qs.z);
    } else {
        e = make_float4(0.0f, 0.0f, __uint_as_float(0x7fc00000u),
                        __uint_as_float((unsigned int)ib));
    }
    ((float4*)(wsf + WS_FTAB))[b] = e;
}

// ---------------------------------------------------------------------------
// main kernel: hot path = ONE ds_read_b128 + ~12 VALU per query.
// ---------------------------------------------------------------------------
__global__ __launch_bounds__(1024, 8) void interp_kernel(
        const f4v* __restrict__ xq, f4v* __restrict__ out,
        const float* __restrict__ wsf, int n4)
{
    __shared__ __align__(16) f4v  ftab[NB];        // 64 KB
    __shared__ float sxp_s[NK + 8];                // 4.1 KB -> 68 KB, 2 blk/CU,
    const int t = threadIdx.x;                     // 32 waves = 100% occupancy
    {
        const f4v* fsrc = (const f4v*)(wsf + WS_FTAB);
        #pragma unroll
        for (int i = 0; i < 4; ++i) ftab[t + 1024 * i] = fsrc[t + 1024 * i];
        sxp_s[t] = wsf[WS_SXP + t];
        if (t < 8) sxp_s[NK + t] = INFINITY;
    }
    const float lo    = wsf[WS_META + 0];
    const float scale = wsf[WS_META + 1];
    const float yp0   = wsf[WS_META + 2];
    const float ypN   = wsf[WS_META + 3];
    const float xpN   = wsf[WS_META + 4];
    const float4* gquads = (const float4*)(wsf + WS_QUAD);
    __syncthreads();

    const int stride = gridDim.x * 1024;
    int q = blockIdx.x * 1024 + t;
    if (q >= n4) return;

    f4v xc = xq[q];
    for (;;) {
        const int qn = q + stride;
        const bool more = qn < n4;
        f4v xn = more ? xq[qn] : xc;               // prefetch next (hides HBM lat)

        float xin[4] = {xc.x, xc.y, xc.z, xc.w};
        f4v ed[4];
        #pragma unroll
        for (int u = 0; u < 4; ++u) {              // 4 gathers issued back-to-back
            int b = bucket_of(xin[u], lo, scale);
            ed[u] = ftab[b];
        }
        float res[4];
        bool  fb[4];
        #pragma unroll
        for (int u = 0; u < 4; ++u) {
            float a = (xin[u] < ed[u].x) ? ed[u].z : ed[u].w;
            res[u]  = __fmaf_rn(xin[u] - ed[u].x, a, ed[u].y);
            fb[u]   = __builtin_isnan(ed[u].z) && (xin[u] > lo) && (xin[u] <= xpN);
        }
        // rare fallback (~2% of lanes): LDS scan + one L2-resident quad read
        #pragma unroll
        for (int u = 0; u < 4; ++u) {
            if (fb[u]) {
                int j = (int)__float_as_uint(ed[u].w);
                while (sxp_s[j] < xin[u]) ++j;     // stops by j=NK-1 (x<=xpN)
                float4 qd = gquads[j - 1];
                res[u] = __fmaf_rn(xin[u] - qd.x, qd.z, qd.y);
            }
        }
        #pragma unroll
        for (int u = 0; u < 4; ++u) {
            res[u] = (xin[u] <= lo)  ? yp0 : res[u];   // searchsorted idx == 0
            res[u] = (xin[u] >  xpN) ? ypN : res[u];   // idx == n
        }
        f4v r = {res[0], res[1], res[2], res[3]};
        __builtin_nontemporal_store(r, &out[q]);

        if (!more) break;
        xc = xn; q = qn;
    }
}

extern "C" void kernel_launch(void* const* d_in, const int* in_sizes, int n_in,
                              void* d_out, int out_size, void* d_ws, size_t ws_size,
                              hipStream_t stream)
{
    const float* x  = (const float*)d_in[0];
    const float* xp = (const float*)d_in[1];
    const float* yp = (const float*)d_in[2];
    float* out = (float*)d_out;
    float* wsf = (float*)d_ws;

    setup_sort<<<1, 1024, 0, stream>>>(xp, yp, wsf);
    setup_tables<<<NB / 256, 256, 0, stream>>>(wsf);

    const int n4 = out_size / 4;   // 33,554,432 / 4 = 8,388,608
    // 512 blocks x 1024 = 2 blocks/CU exact residency; 16 f4v per thread
    interp_kernel<<<512, 1024, 0, stream>>>((const f4v*)x, (f4v*)out, wsf, n4);
}